// Round 1
// baseline (2738.894 us; speedup 1.0000x reference)
//
#include <hip/hip_runtime.h>

#define NF 128           // feature dim (fixed by problem)
#define GEMM_ROWS 32     // feature rows per block in GEMM

// ---------------------------------------------------------------------------
// Detect whether edge_index is int64 (high 32-bit words all zero) or int32.
// Indices are < 100000 < 2^31, so for int64 every odd 32-bit word is 0.
// For int32 the odd words are real indices (prob. all-64-zero ~ 1e-320).
// ---------------------------------------------------------------------------
__global__ __launch_bounds__(64) void detect_kernel(const int* __restrict__ ei_words,
                                                    int* __restrict__ flag) {
    if (threadIdx.x == 0) {
        int all_zero = 1;
        for (int i = 0; i < 64; ++i) {
            if (ei_words[2 * i + 1] != 0) { all_zero = 0; break; }
        }
        *flag = all_zero;  // 1 => int64 layout
    }
}

// ---------------------------------------------------------------------------
// out[n][f] = bias[f]   (or = feature[n][f] if num_modal <= 1)
// ---------------------------------------------------------------------------
__global__ __launch_bounds__(256) void init_kernel(const float* __restrict__ bias,
                                                   const float* __restrict__ feat,
                                                   float* __restrict__ out,
                                                   int total4,
                                                   const int* __restrict__ nm) {
    int idx = blockIdx.x * 256 + threadIdx.x;
    if (idx >= total4) return;
    if (*nm > 1)
        ((float4*)out)[idx] = ((const float4*)bias)[idx & (NF / 4 - 1)];
    else
        ((float4*)out)[idx] = ((const float4*)feat)[idx];
}

// ---------------------------------------------------------------------------
// support = feature @ W      (fp32, vector ALU; K=F=128)
// Block: 256 threads, 32 rows x 128 cols. Thread tile 4x4.
// LDS: 16 KB feature tile + 16 KB W k-tile = 32 KB -> good occupancy.
// N = 100000 is divisible by GEMM_ROWS=32, so no row guards needed.
// ---------------------------------------------------------------------------
__global__ __launch_bounds__(256) void gemm_kernel(const float* __restrict__ feat,
                                                   const float* __restrict__ W,
                                                   float* __restrict__ support,
                                                   int N) {
    __shared__ float Flds[GEMM_ROWS * NF];   // 16 KB
    __shared__ float Wlds[32 * NF];          // 16 KB (k-tile of 32)
    int tid = threadIdx.x;
    int row0 = blockIdx.x * GEMM_ROWS;

    // stage 32 feature rows (4096 floats = 1024 float4)
    const float4* f4p = (const float4*)(feat + (size_t)row0 * NF);
    float4* Fl4 = (float4*)Flds;
#pragma unroll
    for (int i = 0; i < 4; ++i) Fl4[tid + i * 256] = f4p[tid + i * 256];

    int tx = tid & 31;        // col group: cols tx*4 .. tx*4+3
    int ty = tid >> 5;        // row group: rows ty*4 .. ty*4+3
    float acc[4][4] = {{0.f}};

    float4* Wl4 = (float4*)Wlds;
    for (int kt = 0; kt < 4; ++kt) {
        __syncthreads();  // protect Wlds against previous-iter readers
        const float4* w4p = (const float4*)(W + kt * 32 * NF);
#pragma unroll
        for (int i = 0; i < 4; ++i) Wl4[tid + i * 256] = w4p[tid + i * 256];
        __syncthreads();
#pragma unroll
        for (int kk = 0; kk < 32; ++kk) {
            int k = kt * 32 + kk;
            float4 wv = *(const float4*)(Wlds + kk * NF + tx * 4);
#pragma unroll
            for (int i = 0; i < 4; ++i) {
                float fv = Flds[(ty * 4 + i) * NF + k];
                acc[i][0] += fv * wv.x;
                acc[i][1] += fv * wv.y;
                acc[i][2] += fv * wv.z;
                acc[i][3] += fv * wv.w;
            }
        }
    }

#pragma unroll
    for (int i = 0; i < 4; ++i) {
        int row = row0 + ty * 4 + i;
        if (row < N) {
            float4 o = make_float4(acc[i][0], acc[i][1], acc[i][2], acc[i][3]);
            *(float4*)(support + (size_t)row * NF + tx * 4) = o;
        }
    }
}

// ---------------------------------------------------------------------------
// scatter: out[dst] += w_e * support[src]
// One 32-lane group per edge; each thread owns a float4 of the 128-wide row.
// ---------------------------------------------------------------------------
__global__ __launch_bounds__(256) void scatter_kernel(const void* __restrict__ ei_raw,
                                                      const float* __restrict__ ew,
                                                      const float* __restrict__ support,
                                                      float* __restrict__ out,
                                                      int E,
                                                      const int* __restrict__ flag,
                                                      const int* __restrict__ nm) {
    if (*nm <= 1) return;
    int is64 = *flag;
    long long idx = (long long)blockIdx.x * 256 + threadIdx.x;
    int e = (int)(idx >> 5);
    if (e >= E) return;
    int f4 = (int)(idx & 31);

    long long dst, src;
    if (is64) {
        const long long* ei = (const long long*)ei_raw;
        dst = ei[e];
        src = ei[E + e];
    } else {
        const int* ei = (const int*)ei_raw;
        dst = ei[e];
        src = ei[E + e];
    }
    float w = ew[e];
    float4 s = *(const float4*)(support + src * NF + f4 * 4);
    float* o = out + dst * NF + f4 * 4;
    atomicAdd(o + 0, w * s.x);
    atomicAdd(o + 1, w * s.y);
    atomicAdd(o + 2, w * s.z);
    atomicAdd(o + 3, w * s.w);
}

// ---------------------------------------------------------------------------
extern "C" void kernel_launch(void* const* d_in, const int* in_sizes, int n_in,
                              void* d_out, int out_size, void* d_ws, size_t ws_size,
                              hipStream_t stream) {
    const float* feat = (const float*)d_in[0];
    const void*  ei   = d_in[1];
    const float* ew   = (const float*)d_in[2];
    const float* W    = (const float*)d_in[3];
    const float* bias = (const float*)d_in[4];
    const int*   nm   = (const int*)d_in[5];

    int N = in_sizes[0] / NF;       // 100000
    int E = in_sizes[2];            // 1600000

    float* support = (float*)d_ws;                                   // N*NF floats
    int*   flag    = (int*)((char*)d_ws + (size_t)N * NF * sizeof(float));

    detect_kernel<<<1, 64, 0, stream>>>((const int*)ei, flag);

    int total4 = N * (NF / 4);
    init_kernel<<<(total4 + 255) / 256, 256, 0, stream>>>(bias, feat, (float*)d_out,
                                                          total4, nm);

    gemm_kernel<<<(N + GEMM_ROWS - 1) / GEMM_ROWS, 256, 0, stream>>>(feat, W, support, N);

    long long sthreads = (long long)E * 32;
    int sblocks = (int)((sthreads + 255) / 256);
    scatter_kernel<<<sblocks, 256, 0, stream>>>(ei, ew, support, (float*)d_out, E,
                                                flag, nm);
}

// Round 2
// 593.152 us; speedup vs baseline: 4.6175x; 4.6175x over previous
//
#include <hip/hip_runtime.h>

#define NF 128           // feature dim (fixed by problem)
#define GEMM_ROWS 32     // feature rows per block in GEMM
#define SCAN_T 1024

// ---------------------------------------------------------------------------
// Detect whether edge_index is int64 (high 32-bit words all zero) or int32.
// ---------------------------------------------------------------------------
__global__ __launch_bounds__(64) void detect_kernel(const int* __restrict__ ei_words,
                                                    int* __restrict__ flag) {
    if (threadIdx.x == 0) {
        int all_zero = 1;
        for (int i = 0; i < 64; ++i) {
            if (ei_words[2 * i + 1] != 0) { all_zero = 0; break; }
        }
        *flag = all_zero;  // 1 => int64 layout
    }
}

__device__ __forceinline__ int load_idx(const void* ei_raw, long long pos, int is64) {
    if (is64) return (int)((const long long*)ei_raw)[pos];
    return ((const int*)ei_raw)[pos];
}

// ---------------------------------------------------------------------------
__global__ __launch_bounds__(256) void zero_kernel(int* __restrict__ p, int n) {
    int i = blockIdx.x * 256 + threadIdx.x;
    if (i < n) p[i] = 0;
}

// counts[dst]++ for every edge
__global__ __launch_bounds__(256) void count_kernel(const void* __restrict__ ei_raw,
                                                    int* __restrict__ counts, int E,
                                                    const int* __restrict__ flag,
                                                    const int* __restrict__ nm) {
    if (*nm <= 1) return;
    int e = blockIdx.x * 256 + threadIdx.x;
    if (e >= E) return;
    int dst = load_idx(ei_raw, e, *flag);
    atomicAdd(&counts[dst], 1);
}

// single-block exclusive scan of counts -> offs[0..N], cursor copy
__global__ __launch_bounds__(SCAN_T) void scan_kernel(const int* __restrict__ counts,
                                                      int* __restrict__ offs,
                                                      int* __restrict__ cursor, int N) {
    __shared__ int lsum[SCAN_T];
    int tid = threadIdx.x;
    int per = (N + SCAN_T - 1) / SCAN_T;
    int beg = tid * per;
    int end = min(beg + per, N);
    int s = 0;
    for (int i = beg; i < end; ++i) s += counts[i];
    lsum[tid] = s;
    __syncthreads();
    for (int off = 1; off < SCAN_T; off <<= 1) {
        int v = (tid >= off) ? lsum[tid - off] : 0;
        __syncthreads();
        lsum[tid] += v;
        __syncthreads();
    }
    int run = (tid > 0) ? lsum[tid - 1] : 0;  // exclusive prefix of this chunk
    for (int i = beg; i < end; ++i) {
        offs[i] = run;
        cursor[i] = run;
        run += counts[i];
    }
    if (tid == SCAN_T - 1) offs[N] = lsum[SCAN_T - 1];
}

// counting-sort edges into (src_bits, w) records grouped by dst
__global__ __launch_bounds__(256) void fill_kernel(const void* __restrict__ ei_raw,
                                                   const float* __restrict__ ew,
                                                   int* __restrict__ cursor,
                                                   float2* __restrict__ srcw, int E,
                                                   const int* __restrict__ flag,
                                                   const int* __restrict__ nm) {
    if (*nm <= 1) return;
    int e = blockIdx.x * 256 + threadIdx.x;
    if (e >= E) return;
    int is64 = *flag;
    int dst = load_idx(ei_raw, e, is64);
    int src = load_idx(ei_raw, (long long)E + e, is64);
    int pos = atomicAdd(&cursor[dst], 1);
    srcw[pos] = make_float2(__int_as_float(src), ew[e]);
}

// ---------------------------------------------------------------------------
// gather: one 64-lane wave per dst row; lane owns float2 of the 128-wide row.
// out[row] = bias + sum_e w_e * support[src_e]     (no atomics)
// ---------------------------------------------------------------------------
__global__ __launch_bounds__(256) void gather_kernel(const int* __restrict__ offs,
                                                     const float2* __restrict__ srcw,
                                                     const float* __restrict__ support,
                                                     const float* __restrict__ bias,
                                                     const float* __restrict__ feat,
                                                     float* __restrict__ out, int N,
                                                     const int* __restrict__ nm) {
    int gwave = (blockIdx.x * 256 + threadIdx.x) >> 6;
    int lane = threadIdx.x & 63;
    if (gwave >= N) return;
    size_t rowoff = (size_t)gwave * NF + lane * 2;
    if (*nm <= 1) {  // identity path
        *(float2*)(out + rowoff) = *(const float2*)(feat + rowoff);
        return;
    }
    int beg = offs[gwave];
    int end = offs[gwave + 1];
    float2 acc = *(const float2*)(bias + lane * 2);
    int e = beg;
    for (; e + 1 < end; e += 2) {  // 2-edge unroll: two independent loads in flight
        float2 sw0 = srcw[e];
        float2 sw1 = srcw[e + 1];
        const float2* p0 = (const float2*)(support + (size_t)__float_as_int(sw0.x) * NF) + lane;
        const float2* p1 = (const float2*)(support + (size_t)__float_as_int(sw1.x) * NF) + lane;
        float2 s0 = *p0;
        float2 s1 = *p1;
        acc.x = fmaf(sw0.y, s0.x, acc.x);
        acc.y = fmaf(sw0.y, s0.y, acc.y);
        acc.x = fmaf(sw1.y, s1.x, acc.x);
        acc.y = fmaf(sw1.y, s1.y, acc.y);
    }
    if (e < end) {
        float2 sw = srcw[e];
        const float2* p = (const float2*)(support + (size_t)__float_as_int(sw.x) * NF) + lane;
        float2 s = *p;
        acc.x = fmaf(sw.y, s.x, acc.x);
        acc.y = fmaf(sw.y, s.y, acc.y);
    }
    *(float2*)(out + rowoff) = acc;
}

// ---------------------------------------------------------------------------
// support = feature @ W (fp32 vector ALU, unchanged from round 1)
// ---------------------------------------------------------------------------
__global__ __launch_bounds__(256) void gemm_kernel(const float* __restrict__ feat,
                                                   const float* __restrict__ W,
                                                   float* __restrict__ support,
                                                   int N) {
    __shared__ float Flds[GEMM_ROWS * NF];   // 16 KB
    __shared__ float Wlds[32 * NF];          // 16 KB
    int tid = threadIdx.x;
    int row0 = blockIdx.x * GEMM_ROWS;

    const float4* f4p = (const float4*)(feat + (size_t)row0 * NF);
    float4* Fl4 = (float4*)Flds;
#pragma unroll
    for (int i = 0; i < 4; ++i) Fl4[tid + i * 256] = f4p[tid + i * 256];

    int tx = tid & 31;
    int ty = tid >> 5;
    float acc[4][4] = {{0.f}};

    float4* Wl4 = (float4*)Wlds;
    for (int kt = 0; kt < 4; ++kt) {
        __syncthreads();
        const float4* w4p = (const float4*)(W + kt * 32 * NF);
#pragma unroll
        for (int i = 0; i < 4; ++i) Wl4[tid + i * 256] = w4p[tid + i * 256];
        __syncthreads();
#pragma unroll
        for (int kk = 0; kk < 32; ++kk) {
            int k = kt * 32 + kk;
            float4 wv = *(const float4*)(Wlds + kk * NF + tx * 4);
#pragma unroll
            for (int i = 0; i < 4; ++i) {
                float fv = Flds[(ty * 4 + i) * NF + k];
                acc[i][0] += fv * wv.x;
                acc[i][1] += fv * wv.y;
                acc[i][2] += fv * wv.z;
                acc[i][3] += fv * wv.w;
            }
        }
    }

#pragma unroll
    for (int i = 0; i < 4; ++i) {
        int row = row0 + ty * 4 + i;
        if (row < N) {
            float4 o = make_float4(acc[i][0], acc[i][1], acc[i][2], acc[i][3]);
            *(float4*)(support + (size_t)row * NF + tx * 4) = o;
        }
    }
}

// ---------------------------------------------------------------------------
// Fallback (round-1) kernels in case ws_size is too small for CSR buffers.
// ---------------------------------------------------------------------------
__global__ __launch_bounds__(256) void init_kernel(const float* __restrict__ bias,
                                                   const float* __restrict__ feat,
                                                   float* __restrict__ out,
                                                   int total4,
                                                   const int* __restrict__ nm) {
    int idx = blockIdx.x * 256 + threadIdx.x;
    if (idx >= total4) return;
    if (*nm > 1)
        ((float4*)out)[idx] = ((const float4*)bias)[idx & (NF / 4 - 1)];
    else
        ((float4*)out)[idx] = ((const float4*)feat)[idx];
}

__global__ __launch_bounds__(256) void scatter_kernel(const void* __restrict__ ei_raw,
                                                      const float* __restrict__ ew,
                                                      const float* __restrict__ support,
                                                      float* __restrict__ out,
                                                      int E,
                                                      const int* __restrict__ flag,
                                                      const int* __restrict__ nm) {
    if (*nm <= 1) return;
    int is64 = *flag;
    long long idx = (long long)blockIdx.x * 256 + threadIdx.x;
    int e = (int)(idx >> 5);
    if (e >= E) return;
    int f4 = (int)(idx & 31);
    long long dst = load_idx(ei_raw, e, is64);
    long long src = load_idx(ei_raw, (long long)E + e, is64);
    float w = ew[e];
    float4 s = *(const float4*)(support + src * NF + f4 * 4);
    float* o = out + dst * NF + f4 * 4;
    atomicAdd(o + 0, w * s.x);
    atomicAdd(o + 1, w * s.y);
    atomicAdd(o + 2, w * s.z);
    atomicAdd(o + 3, w * s.w);
}

// ---------------------------------------------------------------------------
extern "C" void kernel_launch(void* const* d_in, const int* in_sizes, int n_in,
                              void* d_out, int out_size, void* d_ws, size_t ws_size,
                              hipStream_t stream) {
    const float* feat = (const float*)d_in[0];
    const void*  ei   = d_in[1];
    const float* ew   = (const float*)d_in[2];
    const float* W    = (const float*)d_in[3];
    const float* bias = (const float*)d_in[4];
    const int*   nm   = (const int*)d_in[5];

    int N = in_sizes[0] / NF;       // 100000
    int E = in_sizes[2];            // 1600000

    // workspace layout
    size_t off = 0;
    float*  support = (float*)d_ws;                     off += (size_t)N * NF * sizeof(float);
    float2* srcw    = (float2*)((char*)d_ws + off);     off += (size_t)E * sizeof(float2);
    int*    counts  = (int*)((char*)d_ws + off);        off += (size_t)N * sizeof(int);
    int*    offs    = (int*)((char*)d_ws + off);        off += (size_t)(N + 1) * sizeof(int);
    int*    cursor  = (int*)((char*)d_ws + off);        off += (size_t)N * sizeof(int);
    int*    flag    = (int*)((char*)d_ws + off);        off += sizeof(int);
    bool use_csr = (ws_size >= off);

    detect_kernel<<<1, 64, 0, stream>>>((const int*)ei, flag);
    gemm_kernel<<<(N + GEMM_ROWS - 1) / GEMM_ROWS, 256, 0, stream>>>(feat, W, support, N);

    if (use_csr) {
        zero_kernel<<<(N + 255) / 256, 256, 0, stream>>>(counts, N);
        count_kernel<<<(E + 255) / 256, 256, 0, stream>>>(ei, counts, E, flag, nm);
        scan_kernel<<<1, SCAN_T, 0, stream>>>(counts, offs, cursor, N);
        fill_kernel<<<(E + 255) / 256, 256, 0, stream>>>(ei, ew, cursor, srcw, E, flag, nm);
        long long gthreads = (long long)N * 64;
        gather_kernel<<<(int)((gthreads + 255) / 256), 256, 0, stream>>>(
            offs, srcw, support, bias, feat, (float*)d_out, N, nm);
    } else {
        int total4 = N * (NF / 4);
        init_kernel<<<(total4 + 255) / 256, 256, 0, stream>>>(bias, feat, (float*)d_out,
                                                              total4, nm);
        long long sthreads = (long long)E * 32;
        scatter_kernel<<<(int)((sthreads + 255) / 256), 256, 0, stream>>>(
            ei, ew, support, (float*)d_out, E, flag, nm);
    }
}

// Round 3
// 373.138 us; speedup vs baseline: 7.3402x; 1.5896x over previous
//
#include <hip/hip_runtime.h>

#define NF 128           // feature dim (fixed by problem)
#define GEMM_ROWS 32     // feature rows per block in GEMM
#define SCHUNK 512       // counts handled per scan block (256 threads x 2)

// ---------------------------------------------------------------------------
// Detect whether edge_index is int64 (high 32-bit words all zero) or int32.
// ---------------------------------------------------------------------------
__global__ __launch_bounds__(64) void detect_kernel(const int* __restrict__ ei_words,
                                                    int* __restrict__ flag) {
    if (threadIdx.x == 0) {
        int all_zero = 1;
        for (int i = 0; i < 64; ++i) {
            if (ei_words[2 * i + 1] != 0) { all_zero = 0; break; }
        }
        *flag = all_zero;  // 1 => int64 layout
    }
}

__device__ __forceinline__ int load_idx(const void* ei_raw, long long pos, int is64) {
    if (is64) return (int)((const long long*)ei_raw)[pos];
    return ((const int*)ei_raw)[pos];
}

// ---------------------------------------------------------------------------
__global__ __launch_bounds__(256) void zero_kernel(int* __restrict__ p, int n) {
    int i = blockIdx.x * 256 + threadIdx.x;
    if (i < n) p[i] = 0;
}

// counts[dst]++ for every edge
__global__ __launch_bounds__(256) void count_kernel(const void* __restrict__ ei_raw,
                                                    int* __restrict__ counts, int E,
                                                    const int* __restrict__ flag,
                                                    const int* __restrict__ nm) {
    if (*nm <= 1) return;
    int e = blockIdx.x * 256 + threadIdx.x;
    if (e >= E) return;
    int dst = load_idx(ei_raw, e, *flag);
    atomicAdd(&counts[dst], 1);
}

// ---------------------------------------------------------------------------
// 3-phase multi-block exclusive scan of counts[N] -> offs[N+1], cursor[N]
// ---------------------------------------------------------------------------
// Phase A: block b sums counts[b*SCHUNK .. ) -> bsum[b]
__global__ __launch_bounds__(256) void scanA_kernel(const int* __restrict__ counts,
                                                    int* __restrict__ bsum, int N) {
    int t = threadIdx.x;
    int i0 = blockIdx.x * SCHUNK + t * 2;
    int s = 0;
    if (i0 < N) s += counts[i0];
    if (i0 + 1 < N) s += counts[i0 + 1];
    __shared__ int l[256];
    l[t] = s;
    __syncthreads();
    for (int o = 128; o > 0; o >>= 1) {
        if (t < o) l[t] += l[t + o];
        __syncthreads();
    }
    if (t == 0) bsum[blockIdx.x] = l[0];
}

// Phase B: single 1024-thread block exclusive-scans bsum[NB] -> boff[NB]; offs[N]=total
__global__ __launch_bounds__(1024) void scanB_kernel(const int* __restrict__ bsum,
                                                     int* __restrict__ boff,
                                                     int* __restrict__ offs,
                                                     int NB, int N) {
    __shared__ int l[1024];
    int t = threadIdx.x;
    int v = (t < NB) ? bsum[t] : 0;
    l[t] = v;
    __syncthreads();
    for (int o = 1; o < 1024; o <<= 1) {
        int x = (t >= o) ? l[t - o] : 0;
        __syncthreads();
        l[t] += x;
        __syncthreads();
    }
    if (t < NB) boff[t] = l[t] - v;     // exclusive
    if (t == 1023) offs[N] = l[1023];   // grand total
}

// Phase C: block b scans its chunk with base boff[b], writes offs + cursor
__global__ __launch_bounds__(256) void scanC_kernel(const int* __restrict__ counts,
                                                    const int* __restrict__ boff,
                                                    int* __restrict__ offs,
                                                    int* __restrict__ cursor, int N) {
    int t = threadIdx.x;
    int i0 = blockIdx.x * SCHUNK + t * 2;
    int c0 = (i0 < N) ? counts[i0] : 0;
    int c1 = (i0 + 1 < N) ? counts[i0 + 1] : 0;
    int s = c0 + c1;
    __shared__ int l[256];
    l[t] = s;
    __syncthreads();
    for (int o = 1; o < 256; o <<= 1) {
        int x = (t >= o) ? l[t - o] : 0;
        __syncthreads();
        l[t] += x;
        __syncthreads();
    }
    int base = boff[blockIdx.x] + (l[t] - s);
    if (i0 < N)     { offs[i0] = base;          cursor[i0] = base; }
    if (i0 + 1 < N) { offs[i0 + 1] = base + c0; cursor[i0 + 1] = base + c0; }
}

// ---------------------------------------------------------------------------
// counting-sort edges into (src_bits, w) records grouped by dst
// ---------------------------------------------------------------------------
__global__ __launch_bounds__(256) void fill_kernel(const void* __restrict__ ei_raw,
                                                   const float* __restrict__ ew,
                                                   int* __restrict__ cursor,
                                                   float2* __restrict__ srcw, int E,
                                                   const int* __restrict__ flag,
                                                   const int* __restrict__ nm) {
    if (*nm <= 1) return;
    int e = blockIdx.x * 256 + threadIdx.x;
    if (e >= E) return;
    int is64 = *flag;
    int dst = load_idx(ei_raw, e, is64);
    int src = load_idx(ei_raw, (long long)E + e, is64);
    int pos = atomicAdd(&cursor[dst], 1);
    srcw[pos] = make_float2(__int_as_float(src), ew[e]);
}

// ---------------------------------------------------------------------------
// gather: one 64-lane wave per dst row; lane owns float2 of the 128-wide row.
// out[row] = bias + sum_e w_e * support[src_e]     (no atomics)
// 4-edge unroll for memory-level parallelism.
// ---------------------------------------------------------------------------
__global__ __launch_bounds__(256) void gather_kernel(const int* __restrict__ offs,
                                                     const float2* __restrict__ srcw,
                                                     const float* __restrict__ support,
                                                     const float* __restrict__ bias,
                                                     const float* __restrict__ feat,
                                                     float* __restrict__ out, int N,
                                                     const int* __restrict__ nm) {
    int gwave = (blockIdx.x * 256 + threadIdx.x) >> 6;
    int lane = threadIdx.x & 63;
    if (gwave >= N) return;
    size_t rowoff = (size_t)gwave * NF + lane * 2;
    if (*nm <= 1) {  // identity path
        *(float2*)(out + rowoff) = *(const float2*)(feat + rowoff);
        return;
    }
    int beg = offs[gwave];
    int end = offs[gwave + 1];
    float2 acc = *(const float2*)(bias + lane * 2);
    int e = beg;
    for (; e + 3 < end; e += 4) {
        float2 sw0 = srcw[e];
        float2 sw1 = srcw[e + 1];
        float2 sw2 = srcw[e + 2];
        float2 sw3 = srcw[e + 3];
        float2 s0 = ((const float2*)(support + (size_t)__float_as_int(sw0.x) * NF))[lane];
        float2 s1 = ((const float2*)(support + (size_t)__float_as_int(sw1.x) * NF))[lane];
        float2 s2 = ((const float2*)(support + (size_t)__float_as_int(sw2.x) * NF))[lane];
        float2 s3 = ((const float2*)(support + (size_t)__float_as_int(sw3.x) * NF))[lane];
        acc.x = fmaf(sw0.y, s0.x, acc.x);  acc.y = fmaf(sw0.y, s0.y, acc.y);
        acc.x = fmaf(sw1.y, s1.x, acc.x);  acc.y = fmaf(sw1.y, s1.y, acc.y);
        acc.x = fmaf(sw2.y, s2.x, acc.x);  acc.y = fmaf(sw2.y, s2.y, acc.y);
        acc.x = fmaf(sw3.y, s3.x, acc.x);  acc.y = fmaf(sw3.y, s3.y, acc.y);
    }
    for (; e < end; ++e) {
        float2 sw = srcw[e];
        float2 s = ((const float2*)(support + (size_t)__float_as_int(sw.x) * NF))[lane];
        acc.x = fmaf(sw.y, s.x, acc.x);
        acc.y = fmaf(sw.y, s.y, acc.y);
    }
    *(float2*)(out + rowoff) = acc;
}

// ---------------------------------------------------------------------------
// support = feature @ W (fp32 vector ALU)
// ---------------------------------------------------------------------------
__global__ __launch_bounds__(256) void gemm_kernel(const float* __restrict__ feat,
                                                   const float* __restrict__ W,
                                                   float* __restrict__ support,
                                                   int N) {
    __shared__ float Flds[GEMM_ROWS * NF];   // 16 KB
    __shared__ float Wlds[32 * NF];          // 16 KB
    int tid = threadIdx.x;
    int row0 = blockIdx.x * GEMM_ROWS;

    const float4* f4p = (const float4*)(feat + (size_t)row0 * NF);
    float4* Fl4 = (float4*)Flds;
#pragma unroll
    for (int i = 0; i < 4; ++i) Fl4[tid + i * 256] = f4p[tid + i * 256];

    int tx = tid & 31;
    int ty = tid >> 5;
    float acc[4][4] = {{0.f}};

    float4* Wl4 = (float4*)Wlds;
    for (int kt = 0; kt < 4; ++kt) {
        __syncthreads();
        const float4* w4p = (const float4*)(W + kt * 32 * NF);
#pragma unroll
        for (int i = 0; i < 4; ++i) Wl4[tid + i * 256] = w4p[tid + i * 256];
        __syncthreads();
#pragma unroll
        for (int kk = 0; kk < 32; ++kk) {
            int k = kt * 32 + kk;
            float4 wv = *(const float4*)(Wlds + kk * NF + tx * 4);
#pragma unroll
            for (int i = 0; i < 4; ++i) {
                float fv = Flds[(ty * 4 + i) * NF + k];
                acc[i][0] += fv * wv.x;
                acc[i][1] += fv * wv.y;
                acc[i][2] += fv * wv.z;
                acc[i][3] += fv * wv.w;
            }
        }
    }

#pragma unroll
    for (int i = 0; i < 4; ++i) {
        int row = row0 + ty * 4 + i;
        if (row < N) {
            float4 o = make_float4(acc[i][0], acc[i][1], acc[i][2], acc[i][3]);
            *(float4*)(support + (size_t)row * NF + tx * 4) = o;
        }
    }
}

// ---------------------------------------------------------------------------
// Fallback (round-1) kernels in case ws_size is too small for CSR buffers.
// ---------------------------------------------------------------------------
__global__ __launch_bounds__(256) void init_kernel(const float* __restrict__ bias,
                                                   const float* __restrict__ feat,
                                                   float* __restrict__ out,
                                                   int total4,
                                                   const int* __restrict__ nm) {
    int idx = blockIdx.x * 256 + threadIdx.x;
    if (idx >= total4) return;
    if (*nm > 1)
        ((float4*)out)[idx] = ((const float4*)bias)[idx & (NF / 4 - 1)];
    else
        ((float4*)out)[idx] = ((const float4*)feat)[idx];
}

__global__ __launch_bounds__(256) void scatter_kernel(const void* __restrict__ ei_raw,
                                                      const float* __restrict__ ew,
                                                      const float* __restrict__ support,
                                                      float* __restrict__ out,
                                                      int E,
                                                      const int* __restrict__ flag,
                                                      const int* __restrict__ nm) {
    if (*nm <= 1) return;
    int is64 = *flag;
    long long idx = (long long)blockIdx.x * 256 + threadIdx.x;
    int e = (int)(idx >> 5);
    if (e >= E) return;
    int f4 = (int)(idx & 31);
    long long dst = load_idx(ei_raw, e, is64);
    long long src = load_idx(ei_raw, (long long)E + e, is64);
    float w = ew[e];
    float4 s = *(const float4*)(support + src * NF + f4 * 4);
    float* o = out + dst * NF + f4 * 4;
    atomicAdd(o + 0, w * s.x);
    atomicAdd(o + 1, w * s.y);
    atomicAdd(o + 2, w * s.z);
    atomicAdd(o + 3, w * s.w);
}

// ---------------------------------------------------------------------------
extern "C" void kernel_launch(void* const* d_in, const int* in_sizes, int n_in,
                              void* d_out, int out_size, void* d_ws, size_t ws_size,
                              hipStream_t stream) {
    const float* feat = (const float*)d_in[0];
    const void*  ei   = d_in[1];
    const float* ew   = (const float*)d_in[2];
    const float* W    = (const float*)d_in[3];
    const float* bias = (const float*)d_in[4];
    const int*   nm   = (const int*)d_in[5];

    int N = in_sizes[0] / NF;       // 100000
    int E = in_sizes[2];            // 1600000
    int NB = (N + SCHUNK - 1) / SCHUNK;   // scan blocks (196); must be <= 1024

    // workspace layout
    size_t off = 0;
    float*  support = (float*)d_ws;                     off += (size_t)N * NF * sizeof(float);
    float2* srcw    = (float2*)((char*)d_ws + off);     off += (size_t)E * sizeof(float2);
    int*    counts  = (int*)((char*)d_ws + off);        off += (size_t)N * sizeof(int);
    int*    offs    = (int*)((char*)d_ws + off);        off += (size_t)(N + 1) * sizeof(int);
    int*    cursor  = (int*)((char*)d_ws + off);        off += (size_t)N * sizeof(int);
    int*    bsum    = (int*)((char*)d_ws + off);        off += (size_t)NB * sizeof(int);
    int*    boff    = (int*)((char*)d_ws + off);        off += (size_t)NB * sizeof(int);
    int*    flag    = (int*)((char*)d_ws + off);        off += sizeof(int);
    bool use_csr = (ws_size >= off) && (NB <= 1024);

    detect_kernel<<<1, 64, 0, stream>>>((const int*)ei, flag);
    gemm_kernel<<<(N + GEMM_ROWS - 1) / GEMM_ROWS, 256, 0, stream>>>(feat, W, support, N);

    if (use_csr) {
        zero_kernel<<<(N + 255) / 256, 256, 0, stream>>>(counts, N);
        count_kernel<<<(E + 255) / 256, 256, 0, stream>>>(ei, counts, E, flag, nm);
        scanA_kernel<<<NB, 256, 0, stream>>>(counts, bsum, N);
        scanB_kernel<<<1, 1024, 0, stream>>>(bsum, boff, offs, NB, N);
        scanC_kernel<<<NB, 256, 0, stream>>>(counts, boff, offs, cursor, N);
        fill_kernel<<<(E + 255) / 256, 256, 0, stream>>>(ei, ew, cursor, srcw, E, flag, nm);
        long long gthreads = (long long)N * 64;
        gather_kernel<<<(int)((gthreads + 255) / 256), 256, 0, stream>>>(
            offs, srcw, support, bias, feat, (float*)d_out, N, nm);
    } else {
        int total4 = N * (NF / 4);
        init_kernel<<<(total4 + 255) / 256, 256, 0, stream>>>(bias, feat, (float*)d_out,
                                                              total4, nm);
        long long sthreads = (long long)E * 32;
        scatter_kernel<<<(int)((sthreads + 255) / 256), 256, 0, stream>>>(
            ei, ew, support, (float*)d_out, E, flag, nm);
    }
}

// Round 4
// 325.788 us; speedup vs baseline: 8.4070x; 1.1453x over previous
//
#include <hip/hip_runtime.h>

#define NF 128           // feature dim (fixed by problem)
#define GEMM_ROWS 32     // feature rows per block in GEMM
#define SCHUNK 512       // counts handled per scan block (256 threads x 2)
#define NWIN 8           // dst windows for XCD-local fill (== # XCDs)
#define FCHUNK 2048      // edges per fill chunk

// ---------------------------------------------------------------------------
// Detect whether edge_index is int64 (high 32-bit words all zero) or int32.
// ---------------------------------------------------------------------------
__global__ __launch_bounds__(64) void detect_kernel(const int* __restrict__ ei_words,
                                                    int* __restrict__ flag) {
    if (threadIdx.x == 0) {
        int all_zero = 1;
        for (int i = 0; i < 64; ++i) {
            if (ei_words[2 * i + 1] != 0) { all_zero = 0; break; }
        }
        *flag = all_zero;  // 1 => int64 layout
    }
}

__device__ __forceinline__ int load_idx(const void* ei_raw, long long pos, int is64) {
    if (is64) return (int)((const long long*)ei_raw)[pos];
    return ((const int*)ei_raw)[pos];
}

// ---------------------------------------------------------------------------
__global__ __launch_bounds__(256) void zero_kernel(int* __restrict__ p, int n) {
    int i = blockIdx.x * 256 + threadIdx.x;
    if (i < n) p[i] = 0;
}

// counts[dst]++ for every edge
__global__ __launch_bounds__(256) void count_kernel(const void* __restrict__ ei_raw,
                                                    int* __restrict__ counts, int E,
                                                    const int* __restrict__ flag,
                                                    const int* __restrict__ nm) {
    if (*nm <= 1) return;
    int e = blockIdx.x * 256 + threadIdx.x;
    if (e >= E) return;
    int dst = load_idx(ei_raw, e, *flag);
    atomicAdd(&counts[dst], 1);
}

// ---------------------------------------------------------------------------
// 3-phase multi-block exclusive scan of counts[N] -> offs[N+1], cursor[N]
// ---------------------------------------------------------------------------
__global__ __launch_bounds__(256) void scanA_kernel(const int* __restrict__ counts,
                                                    int* __restrict__ bsum, int N) {
    int t = threadIdx.x;
    int i0 = blockIdx.x * SCHUNK + t * 2;
    int s = 0;
    if (i0 < N) s += counts[i0];
    if (i0 + 1 < N) s += counts[i0 + 1];
    __shared__ int l[256];
    l[t] = s;
    __syncthreads();
    for (int o = 128; o > 0; o >>= 1) {
        if (t < o) l[t] += l[t + o];
        __syncthreads();
    }
    if (t == 0) bsum[blockIdx.x] = l[0];
}

__global__ __launch_bounds__(1024) void scanB_kernel(const int* __restrict__ bsum,
                                                     int* __restrict__ boff,
                                                     int* __restrict__ offs,
                                                     int NB, int N) {
    __shared__ int l[1024];
    int t = threadIdx.x;
    int v = (t < NB) ? bsum[t] : 0;
    l[t] = v;
    __syncthreads();
    for (int o = 1; o < 1024; o <<= 1) {
        int x = (t >= o) ? l[t - o] : 0;
        __syncthreads();
        l[t] += x;
        __syncthreads();
    }
    if (t < NB) boff[t] = l[t] - v;     // exclusive
    if (t == 1023) offs[N] = l[1023];   // grand total
}

__global__ __launch_bounds__(256) void scanC_kernel(const int* __restrict__ counts,
                                                    const int* __restrict__ boff,
                                                    int* __restrict__ offs,
                                                    int* __restrict__ cursor, int N) {
    int t = threadIdx.x;
    int i0 = blockIdx.x * SCHUNK + t * 2;
    int c0 = (i0 < N) ? counts[i0] : 0;
    int c1 = (i0 + 1 < N) ? counts[i0 + 1] : 0;
    int s = c0 + c1;
    __shared__ int l[256];
    l[t] = s;
    __syncthreads();
    for (int o = 1; o < 256; o <<= 1) {
        int x = (t >= o) ? l[t - o] : 0;
        __syncthreads();
        l[t] += x;
        __syncthreads();
    }
    int base = boff[blockIdx.x] + (l[t] - s);
    if (i0 < N)     { offs[i0] = base;          cursor[i0] = base; }
    if (i0 + 1 < N) { offs[i0 + 1] = base + c0; cursor[i0 + 1] = base + c0; }
}

// ---------------------------------------------------------------------------
// counting-sort edges into (src_bits, w) records grouped by dst.
// XCD-windowed: block handles window (blockIdx.x % NWIN); with round-robin
// block->XCD dispatch, each srcw region (12.8MB/NWIN = 1.6MB) is written by
// exactly one XCD and accumulates full 64B lines in that XCD's L2 before
// writeback (kernel-end release flushes L2 for the next kernel's reads).
// ---------------------------------------------------------------------------
__global__ __launch_bounds__(256) void fill_kernel(const void* __restrict__ ei_raw,
                                                   const float* __restrict__ ew,
                                                   int* __restrict__ cursor,
                                                   float2* __restrict__ srcw, int E,
                                                   int N,
                                                   const int* __restrict__ flag,
                                                   const int* __restrict__ nm) {
    if (*nm <= 1) return;
    int is64 = *flag;
    int win   = blockIdx.x % NWIN;          // -> XCD (round-robin heuristic)
    int chunk = blockIdx.x / NWIN;
    int span = (N + NWIN - 1) / NWIN;
    int lo = win * span;
    int hi = min(lo + span, N);
    int ebeg = chunk * FCHUNK;
    int eend = min(ebeg + FCHUNK, E);
    for (int e = ebeg + threadIdx.x; e < eend; e += 256) {
        int dst = load_idx(ei_raw, e, is64);
        if (dst < lo || dst >= hi) continue;
        int src = load_idx(ei_raw, (long long)E + e, is64);
        int pos = atomicAdd(&cursor[dst], 1);
        srcw[pos] = make_float2(__int_as_float(src), ew[e]);
    }
}

// ---------------------------------------------------------------------------
// gather: one 64-lane wave per dst row; lane owns float2 of the 128-wide row.
// out[row] = bias + sum_e w_e * support[src_e]     (no atomics)
// ---------------------------------------------------------------------------
__global__ __launch_bounds__(256) void gather_kernel(const int* __restrict__ offs,
                                                     const float2* __restrict__ srcw,
                                                     const float* __restrict__ support,
                                                     const float* __restrict__ bias,
                                                     const float* __restrict__ feat,
                                                     float* __restrict__ out, int N,
                                                     const int* __restrict__ nm) {
    int gwave = (blockIdx.x * 256 + threadIdx.x) >> 6;
    int lane = threadIdx.x & 63;
    if (gwave >= N) return;
    size_t rowoff = (size_t)gwave * NF + lane * 2;
    if (*nm <= 1) {  // identity path
        *(float2*)(out + rowoff) = *(const float2*)(feat + rowoff);
        return;
    }
    int beg = offs[gwave];
    int end = offs[gwave + 1];
    float2 acc = *(const float2*)(bias + lane * 2);
    int e = beg;
    for (; e + 3 < end; e += 4) {
        float2 sw0 = srcw[e];
        float2 sw1 = srcw[e + 1];
        float2 sw2 = srcw[e + 2];
        float2 sw3 = srcw[e + 3];
        float2 s0 = ((const float2*)(support + (size_t)__float_as_int(sw0.x) * NF))[lane];
        float2 s1 = ((const float2*)(support + (size_t)__float_as_int(sw1.x) * NF))[lane];
        float2 s2 = ((const float2*)(support + (size_t)__float_as_int(sw2.x) * NF))[lane];
        float2 s3 = ((const float2*)(support + (size_t)__float_as_int(sw3.x) * NF))[lane];
        acc.x = fmaf(sw0.y, s0.x, acc.x);  acc.y = fmaf(sw0.y, s0.y, acc.y);
        acc.x = fmaf(sw1.y, s1.x, acc.x);  acc.y = fmaf(sw1.y, s1.y, acc.y);
        acc.x = fmaf(sw2.y, s2.x, acc.x);  acc.y = fmaf(sw2.y, s2.y, acc.y);
        acc.x = fmaf(sw3.y, s3.x, acc.x);  acc.y = fmaf(sw3.y, s3.y, acc.y);
    }
    for (; e < end; ++e) {
        float2 sw = srcw[e];
        float2 s = ((const float2*)(support + (size_t)__float_as_int(sw.x) * NF))[lane];
        acc.x = fmaf(sw.y, s.x, acc.x);
        acc.y = fmaf(sw.y, s.y, acc.y);
    }
    *(float2*)(out + rowoff) = acc;
}

// ---------------------------------------------------------------------------
// support = feature @ W (fp32 vector ALU)
// ---------------------------------------------------------------------------
__global__ __launch_bounds__(256) void gemm_kernel(const float* __restrict__ feat,
                                                   const float* __restrict__ W,
                                                   float* __restrict__ support,
                                                   int N) {
    __shared__ float Flds[GEMM_ROWS * NF];   // 16 KB
    __shared__ float Wlds[32 * NF];          // 16 KB
    int tid = threadIdx.x;
    int row0 = blockIdx.x * GEMM_ROWS;

    const float4* f4p = (const float4*)(feat + (size_t)row0 * NF);
    float4* Fl4 = (float4*)Flds;
#pragma unroll
    for (int i = 0; i < 4; ++i) Fl4[tid + i * 256] = f4p[tid + i * 256];

    int tx = tid & 31;
    int ty = tid >> 5;
    float acc[4][4] = {{0.f}};

    float4* Wl4 = (float4*)Wlds;
    for (int kt = 0; kt < 4; ++kt) {
        __syncthreads();
        const float4* w4p = (const float4*)(W + kt * 32 * NF);
#pragma unroll
        for (int i = 0; i < 4; ++i) Wl4[tid + i * 256] = w4p[tid + i * 256];
        __syncthreads();
#pragma unroll
        for (int kk = 0; kk < 32; ++kk) {
            int k = kt * 32 + kk;
            float4 wv = *(const float4*)(Wlds + kk * NF + tx * 4);
#pragma unroll
            for (int i = 0; i < 4; ++i) {
                float fv = Flds[(ty * 4 + i) * NF + k];
                acc[i][0] += fv * wv.x;
                acc[i][1] += fv * wv.y;
                acc[i][2] += fv * wv.z;
                acc[i][3] += fv * wv.w;
            }
        }
    }

#pragma unroll
    for (int i = 0; i < 4; ++i) {
        int row = row0 + ty * 4 + i;
        if (row < N) {
            float4 o = make_float4(acc[i][0], acc[i][1], acc[i][2], acc[i][3]);
            *(float4*)(support + (size_t)row * NF + tx * 4) = o;
        }
    }
}

// ---------------------------------------------------------------------------
// Fallback (round-1) kernels in case ws_size is too small for CSR buffers.
// ---------------------------------------------------------------------------
__global__ __launch_bounds__(256) void init_kernel(const float* __restrict__ bias,
                                                   const float* __restrict__ feat,
                                                   float* __restrict__ out,
                                                   int total4,
                                                   const int* __restrict__ nm) {
    int idx = blockIdx.x * 256 + threadIdx.x;
    if (idx >= total4) return;
    if (*nm > 1)
        ((float4*)out)[idx] = ((const float4*)bias)[idx & (NF / 4 - 1)];
    else
        ((float4*)out)[idx] = ((const float4*)feat)[idx];
}

__global__ __launch_bounds__(256) void scatter_kernel(const void* __restrict__ ei_raw,
                                                      const float* __restrict__ ew,
                                                      const float* __restrict__ support,
                                                      float* __restrict__ out,
                                                      int E,
                                                      const int* __restrict__ flag,
                                                      const int* __restrict__ nm) {
    if (*nm <= 1) return;
    int is64 = *flag;
    long long idx = (long long)blockIdx.x * 256 + threadIdx.x;
    int e = (int)(idx >> 5);
    if (e >= E) return;
    int f4 = (int)(idx & 31);
    long long dst = load_idx(ei_raw, e, is64);
    long long src = load_idx(ei_raw, (long long)E + e, is64);
    float w = ew[e];
    float4 s = *(const float4*)(support + src * NF + f4 * 4);
    float* o = out + dst * NF + f4 * 4;
    atomicAdd(o + 0, w * s.x);
    atomicAdd(o + 1, w * s.y);
    atomicAdd(o + 2, w * s.z);
    atomicAdd(o + 3, w * s.w);
}

// ---------------------------------------------------------------------------
extern "C" void kernel_launch(void* const* d_in, const int* in_sizes, int n_in,
                              void* d_out, int out_size, void* d_ws, size_t ws_size,
                              hipStream_t stream) {
    const float* feat = (const float*)d_in[0];
    const void*  ei   = d_in[1];
    const float* ew   = (const float*)d_in[2];
    const float* W    = (const float*)d_in[3];
    const float* bias = (const float*)d_in[4];
    const int*   nm   = (const int*)d_in[5];

    int N = in_sizes[0] / NF;       // 100000
    int E = in_sizes[2];            // 1600000
    int NB = (N + SCHUNK - 1) / SCHUNK;   // scan blocks (196); must be <= 1024

    // workspace layout
    size_t off = 0;
    float*  support = (float*)d_ws;                     off += (size_t)N * NF * sizeof(float);
    float2* srcw    = (float2*)((char*)d_ws + off);     off += (size_t)E * sizeof(float2);
    int*    counts  = (int*)((char*)d_ws + off);        off += (size_t)N * sizeof(int);
    int*    offs    = (int*)((char*)d_ws + off);        off += (size_t)(N + 1) * sizeof(int);
    int*    cursor  = (int*)((char*)d_ws + off);        off += (size_t)N * sizeof(int);
    int*    bsum    = (int*)((char*)d_ws + off);        off += (size_t)NB * sizeof(int);
    int*    boff    = (int*)((char*)d_ws + off);        off += (size_t)NB * sizeof(int);
    int*    flag    = (int*)((char*)d_ws + off);        off += sizeof(int);
    bool use_csr = (ws_size >= off) && (NB <= 1024);

    detect_kernel<<<1, 64, 0, stream>>>((const int*)ei, flag);
    gemm_kernel<<<(N + GEMM_ROWS - 1) / GEMM_ROWS, 256, 0, stream>>>(feat, W, support, N);

    if (use_csr) {
        zero_kernel<<<(N + 255) / 256, 256, 0, stream>>>(counts, N);
        count_kernel<<<(E + 255) / 256, 256, 0, stream>>>(ei, counts, E, flag, nm);
        scanA_kernel<<<NB, 256, 0, stream>>>(counts, bsum, N);
        scanB_kernel<<<1, 1024, 0, stream>>>(bsum, boff, offs, NB, N);
        scanC_kernel<<<NB, 256, 0, stream>>>(counts, boff, offs, cursor, N);
        int nchunks = (E + FCHUNK - 1) / FCHUNK;
        fill_kernel<<<nchunks * NWIN, 256, 0, stream>>>(ei, ew, cursor, srcw, E, N,
                                                        flag, nm);
        long long gthreads = (long long)N * 64;
        gather_kernel<<<(int)((gthreads + 255) / 256), 256, 0, stream>>>(
            offs, srcw, support, bias, feat, (float*)d_out, N, nm);
    } else {
        int total4 = N * (NF / 4);
        init_kernel<<<(total4 + 255) / 256, 256, 0, stream>>>(bias, feat, (float*)d_out,
                                                              total4, nm);
        long long sthreads = (long long)E * 32;
        scatter_kernel<<<(int)((sthreads + 255) / 256), 256, 0, stream>>>(
            ei, ew, support, (float*)d_out, E, flag, nm);
    }
}

// Round 5
// 283.873 us; speedup vs baseline: 9.6483x; 1.1477x over previous
//
#include <hip/hip_runtime.h>
#include <hip/hip_fp16.h>

#define NF 128           // feature dim (fixed by problem)
#define GEMM_ROWS 32     // feature rows per block in GEMM
#define SCHUNK 512       // counts handled per scan block (256 threads x 2)
#define NWIN 8           // dst windows for XCD-local fill (== # XCDs)
#define FCHUNK 2048      // edges per fill chunk

// ---------------------------------------------------------------------------
// Detect whether edge_index is int64 (high 32-bit words all zero) or int32.
// ---------------------------------------------------------------------------
__global__ __launch_bounds__(64) void detect_kernel(const int* __restrict__ ei_words,
                                                    int* __restrict__ flag) {
    if (threadIdx.x == 0) {
        int all_zero = 1;
        for (int i = 0; i < 64; ++i) {
            if (ei_words[2 * i + 1] != 0) { all_zero = 0; break; }
        }
        *flag = all_zero;  // 1 => int64 layout
    }
}

__device__ __forceinline__ int load_idx(const void* ei_raw, long long pos, int is64) {
    if (is64) return (int)((const long long*)ei_raw)[pos];
    return ((const int*)ei_raw)[pos];
}

// ---------------------------------------------------------------------------
__global__ __launch_bounds__(256) void zero_kernel(int* __restrict__ p, int n) {
    int i = blockIdx.x * 256 + threadIdx.x;
    if (i < n) p[i] = 0;
}

// counts[dst]++ for every edge
__global__ __launch_bounds__(256) void count_kernel(const void* __restrict__ ei_raw,
                                                    int* __restrict__ counts, int E,
                                                    const int* __restrict__ flag,
                                                    const int* __restrict__ nm) {
    if (*nm <= 1) return;
    int e = blockIdx.x * 256 + threadIdx.x;
    if (e >= E) return;
    int dst = load_idx(ei_raw, e, *flag);
    atomicAdd(&counts[dst], 1);
}

// ---------------------------------------------------------------------------
// 3-phase multi-block exclusive scan of counts[N] -> offs[N+1], cursor[N]
// ---------------------------------------------------------------------------
__global__ __launch_bounds__(256) void scanA_kernel(const int* __restrict__ counts,
                                                    int* __restrict__ bsum, int N) {
    int t = threadIdx.x;
    int i0 = blockIdx.x * SCHUNK + t * 2;
    int s = 0;
    if (i0 < N) s += counts[i0];
    if (i0 + 1 < N) s += counts[i0 + 1];
    __shared__ int l[256];
    l[t] = s;
    __syncthreads();
    for (int o = 128; o > 0; o >>= 1) {
        if (t < o) l[t] += l[t + o];
        __syncthreads();
    }
    if (t == 0) bsum[blockIdx.x] = l[0];
}

__global__ __launch_bounds__(1024) void scanB_kernel(const int* __restrict__ bsum,
                                                     int* __restrict__ boff,
                                                     int* __restrict__ offs,
                                                     int NB, int N) {
    __shared__ int l[1024];
    int t = threadIdx.x;
    int v = (t < NB) ? bsum[t] : 0;
    l[t] = v;
    __syncthreads();
    for (int o = 1; o < 1024; o <<= 1) {
        int x = (t >= o) ? l[t - o] : 0;
        __syncthreads();
        l[t] += x;
        __syncthreads();
    }
    if (t < NB) boff[t] = l[t] - v;     // exclusive
    if (t == 1023) offs[N] = l[1023];   // grand total
}

__global__ __launch_bounds__(256) void scanC_kernel(const int* __restrict__ counts,
                                                    const int* __restrict__ boff,
                                                    int* __restrict__ offs,
                                                    int* __restrict__ cursor, int N) {
    int t = threadIdx.x;
    int i0 = blockIdx.x * SCHUNK + t * 2;
    int c0 = (i0 < N) ? counts[i0] : 0;
    int c1 = (i0 + 1 < N) ? counts[i0 + 1] : 0;
    int s = c0 + c1;
    __shared__ int l[256];
    l[t] = s;
    __syncthreads();
    for (int o = 1; o < 256; o <<= 1) {
        int x = (t >= o) ? l[t - o] : 0;
        __syncthreads();
        l[t] += x;
        __syncthreads();
    }
    int base = boff[blockIdx.x] + (l[t] - s);
    if (i0 < N)     { offs[i0] = base;          cursor[i0] = base; }
    if (i0 + 1 < N) { offs[i0 + 1] = base + c0; cursor[i0 + 1] = base + c0; }
}

// ---------------------------------------------------------------------------
// counting-sort edges into (src_bits, w) records grouped by dst.
// XCD-windowed (see round-4 note): keeps each srcw region in one XCD's L2.
// ---------------------------------------------------------------------------
__global__ __launch_bounds__(256) void fill_kernel(const void* __restrict__ ei_raw,
                                                   const float* __restrict__ ew,
                                                   int* __restrict__ cursor,
                                                   float2* __restrict__ srcw, int E,
                                                   int N,
                                                   const int* __restrict__ flag,
                                                   const int* __restrict__ nm) {
    if (*nm <= 1) return;
    int is64 = *flag;
    int win   = blockIdx.x % NWIN;          // -> XCD (round-robin heuristic)
    int chunk = blockIdx.x / NWIN;
    int span = (N + NWIN - 1) / NWIN;
    int lo = win * span;
    int hi = min(lo + span, N);
    int ebeg = chunk * FCHUNK;
    int eend = min(ebeg + FCHUNK, E);
    for (int e = ebeg + threadIdx.x; e < eend; e += 256) {
        int dst = load_idx(ei_raw, e, is64);
        if (dst < lo || dst >= hi) continue;
        int src = load_idx(ei_raw, (long long)E + e, is64);
        int pos = atomicAdd(&cursor[dst], 1);
        srcw[pos] = make_float2(__int_as_float(src), ew[e]);
    }
}

// ---------------------------------------------------------------------------
// gather: one 64-lane wave per dst row; lane owns a half2 of the 128-wide row.
// out[row] = bias + sum_e w_e * support_h[src_e]   (fp16 rows, fp32 accumulate)
// ---------------------------------------------------------------------------
__global__ __launch_bounds__(256) void gather_kernel(const int* __restrict__ offs,
                                                     const float2* __restrict__ srcw,
                                                     const __half* __restrict__ support,
                                                     const float* __restrict__ bias,
                                                     const float* __restrict__ feat,
                                                     float* __restrict__ out, int N,
                                                     const int* __restrict__ nm) {
    int gwave = (blockIdx.x * 256 + threadIdx.x) >> 6;
    int lane = threadIdx.x & 63;
    if (gwave >= N) return;
    size_t rowoff = (size_t)gwave * NF + lane * 2;
    if (*nm <= 1) {  // identity path
        *(float2*)(out + rowoff) = *(const float2*)(feat + rowoff);
        return;
    }
    int beg = offs[gwave];
    int end = offs[gwave + 1];
    float2 acc = *(const float2*)(bias + lane * 2);
    int e = beg;
    for (; e + 3 < end; e += 4) {
        float2 sw0 = srcw[e];
        float2 sw1 = srcw[e + 1];
        float2 sw2 = srcw[e + 2];
        float2 sw3 = srcw[e + 3];
        __half2 h0 = ((const __half2*)(support + (size_t)__float_as_int(sw0.x) * NF))[lane];
        __half2 h1 = ((const __half2*)(support + (size_t)__float_as_int(sw1.x) * NF))[lane];
        __half2 h2 = ((const __half2*)(support + (size_t)__float_as_int(sw2.x) * NF))[lane];
        __half2 h3 = ((const __half2*)(support + (size_t)__float_as_int(sw3.x) * NF))[lane];
        float2 s0 = __half22float2(h0);
        float2 s1 = __half22float2(h1);
        float2 s2 = __half22float2(h2);
        float2 s3 = __half22float2(h3);
        acc.x = fmaf(sw0.y, s0.x, acc.x);  acc.y = fmaf(sw0.y, s0.y, acc.y);
        acc.x = fmaf(sw1.y, s1.x, acc.x);  acc.y = fmaf(sw1.y, s1.y, acc.y);
        acc.x = fmaf(sw2.y, s2.x, acc.x);  acc.y = fmaf(sw2.y, s2.y, acc.y);
        acc.x = fmaf(sw3.y, s3.x, acc.x);  acc.y = fmaf(sw3.y, s3.y, acc.y);
    }
    for (; e < end; ++e) {
        float2 sw = srcw[e];
        __half2 h = ((const __half2*)(support + (size_t)__float_as_int(sw.x) * NF))[lane];
        float2 s = __half22float2(h);
        acc.x = fmaf(sw.y, s.x, acc.x);
        acc.y = fmaf(sw.y, s.y, acc.y);
    }
    *(float2*)(out + rowoff) = acc;
}

// ---------------------------------------------------------------------------
// support = feature @ W (fp32 vector ALU, fp16 output rows)
// ---------------------------------------------------------------------------
__global__ __launch_bounds__(256) void gemm_kernel(const float* __restrict__ feat,
                                                   const float* __restrict__ W,
                                                   __half* __restrict__ support,
                                                   int N) {
    __shared__ float Flds[GEMM_ROWS * NF];   // 16 KB
    __shared__ float Wlds[32 * NF];          // 16 KB
    int tid = threadIdx.x;
    int row0 = blockIdx.x * GEMM_ROWS;

    const float4* f4p = (const float4*)(feat + (size_t)row0 * NF);
    float4* Fl4 = (float4*)Flds;
#pragma unroll
    for (int i = 0; i < 4; ++i) Fl4[tid + i * 256] = f4p[tid + i * 256];

    int tx = tid & 31;
    int ty = tid >> 5;
    float acc[4][4] = {{0.f}};

    float4* Wl4 = (float4*)Wlds;
    for (int kt = 0; kt < 4; ++kt) {
        __syncthreads();
        const float4* w4p = (const float4*)(W + kt * 32 * NF);
#pragma unroll
        for (int i = 0; i < 4; ++i) Wl4[tid + i * 256] = w4p[tid + i * 256];
        __syncthreads();
#pragma unroll
        for (int kk = 0; kk < 32; ++kk) {
            int k = kt * 32 + kk;
            float4 wv = *(const float4*)(Wlds + kk * NF + tx * 4);
#pragma unroll
            for (int i = 0; i < 4; ++i) {
                float fv = Flds[(ty * 4 + i) * NF + k];
                acc[i][0] += fv * wv.x;
                acc[i][1] += fv * wv.y;
                acc[i][2] += fv * wv.z;
                acc[i][3] += fv * wv.w;
            }
        }
    }

#pragma unroll
    for (int i = 0; i < 4; ++i) {
        int row = row0 + ty * 4 + i;
        if (row < N) {
            __half2 h0 = __floats2half2_rn(acc[i][0], acc[i][1]);
            __half2 h1 = __floats2half2_rn(acc[i][2], acc[i][3]);
            __half2* sp = (__half2*)(support + (size_t)row * NF + tx * 4);
            sp[0] = h0;
            sp[1] = h1;
        }
    }
}

// ---------------------------------------------------------------------------
// Fallback (round-1) kernels in case ws_size is too small for CSR buffers.
// ---------------------------------------------------------------------------
__global__ __launch_bounds__(256) void init_kernel(const float* __restrict__ bias,
                                                   const float* __restrict__ feat,
                                                   float* __restrict__ out,
                                                   int total4,
                                                   const int* __restrict__ nm) {
    int idx = blockIdx.x * 256 + threadIdx.x;
    if (idx >= total4) return;
    if (*nm > 1)
        ((float4*)out)[idx] = ((const float4*)bias)[idx & (NF / 4 - 1)];
    else
        ((float4*)out)[idx] = ((const float4*)feat)[idx];
}

__global__ __launch_bounds__(256) void scatter_kernel(const void* __restrict__ ei_raw,
                                                      const float* __restrict__ ew,
                                                      const __half* __restrict__ support,
                                                      float* __restrict__ out,
                                                      int E,
                                                      const int* __restrict__ flag,
                                                      const int* __restrict__ nm) {
    if (*nm <= 1) return;
    int is64 = *flag;
    long long idx = (long long)blockIdx.x * 256 + threadIdx.x;
    int e = (int)(idx >> 5);
    if (e >= E) return;
    int f4 = (int)(idx & 31);
    long long dst = load_idx(ei_raw, e, is64);
    long long src = load_idx(ei_raw, (long long)E + e, is64);
    float w = ew[e];
    __half2 h0 = ((const __half2*)(support + src * NF + f4 * 4))[0];
    __half2 h1 = ((const __half2*)(support + src * NF + f4 * 4))[1];
    float2 s0 = __half22float2(h0);
    float2 s1 = __half22float2(h1);
    float* o = out + dst * NF + f4 * 4;
    atomicAdd(o + 0, w * s0.x);
    atomicAdd(o + 1, w * s0.y);
    atomicAdd(o + 2, w * s1.x);
    atomicAdd(o + 3, w * s1.y);
}

// ---------------------------------------------------------------------------
extern "C" void kernel_launch(void* const* d_in, const int* in_sizes, int n_in,
                              void* d_out, int out_size, void* d_ws, size_t ws_size,
                              hipStream_t stream) {
    const float* feat = (const float*)d_in[0];
    const void*  ei   = d_in[1];
    const float* ew   = (const float*)d_in[2];
    const float* W    = (const float*)d_in[3];
    const float* bias = (const float*)d_in[4];
    const int*   nm   = (const int*)d_in[5];

    int N = in_sizes[0] / NF;       // 100000
    int E = in_sizes[2];            // 1600000
    int NB = (N + SCHUNK - 1) / SCHUNK;   // scan blocks (196); must be <= 1024

    // workspace layout
    size_t off = 0;
    __half* support = (__half*)d_ws;                    off += (size_t)N * NF * sizeof(__half);
    float2* srcw    = (float2*)((char*)d_ws + off);     off += (size_t)E * sizeof(float2);
    int*    counts  = (int*)((char*)d_ws + off);        off += (size_t)N * sizeof(int);
    int*    offs    = (int*)((char*)d_ws + off);        off += (size_t)(N + 1) * sizeof(int);
    int*    cursor  = (int*)((char*)d_ws + off);        off += (size_t)N * sizeof(int);
    int*    bsum    = (int*)((char*)d_ws + off);        off += (size_t)NB * sizeof(int);
    int*    boff    = (int*)((char*)d_ws + off);        off += (size_t)NB * sizeof(int);
    int*    flag    = (int*)((char*)d_ws + off);        off += sizeof(int);
    bool use_csr = (ws_size >= off) && (NB <= 1024);

    detect_kernel<<<1, 64, 0, stream>>>((const int*)ei, flag);
    gemm_kernel<<<(N + GEMM_ROWS - 1) / GEMM_ROWS, 256, 0, stream>>>(feat, W, support, N);

    if (use_csr) {
        zero_kernel<<<(N + 255) / 256, 256, 0, stream>>>(counts, N);
        count_kernel<<<(E + 255) / 256, 256, 0, stream>>>(ei, counts, E, flag, nm);
        scanA_kernel<<<NB, 256, 0, stream>>>(counts, bsum, N);
        scanB_kernel<<<1, 1024, 0, stream>>>(bsum, boff, offs, NB, N);
        scanC_kernel<<<NB, 256, 0, stream>>>(counts, boff, offs, cursor, N);
        int nchunks = (E + FCHUNK - 1) / FCHUNK;
        fill_kernel<<<nchunks * NWIN, 256, 0, stream>>>(ei, ew, cursor, srcw, E, N,
                                                        flag, nm);
        long long gthreads = (long long)N * 64;
        gather_kernel<<<(int)((gthreads + 255) / 256), 256, 0, stream>>>(
            offs, srcw, support, bias, feat, (float*)d_out, N, nm);
    } else {
        int total4 = N * (NF / 4);
        init_kernel<<<(total4 + 255) / 256, 256, 0, stream>>>(bias, feat, (float*)d_out,
                                                              total4, nm);
        long long sthreads = (long long)E * 32;
        scatter_kernel<<<(int)((sthreads + 255) / 256), 256, 0, stream>>>(
            ei, ew, support, (float*)d_out, E, flag, nm);
    }
}